// Round 9
// baseline (48.916 us; speedup 1.0000x reference)
//
#include <hip/hip_runtime.h>

#define BATCH 8
#define HH 544
#define WW 960
#define HWSZ (HH * WW)
#define OTX 120           // output tile width (region 128 px = 32 quads)
#define OTY 24            // output tile height (region 32 rows)
#define LROWS 34          // region rows -1..32 at LDS rows 0..33 (0,33 = zero ring)
#define LCELLS 32         // 32 quads per row; x-halo via shfl
#define LBUF (LROWS * LCELLS)
#define NTX2 8            // 960/120 tile columns per image
#define NTY2 23           // ceil(544/24) tile rows per image
#define TPB (NTX2 * NTY2) // 184 tiles per image

static __device__ __forceinline__ void bar() {
    // order LDS only; leave global prefetch loads in flight across the barrier
    asm volatile("s_waitcnt lgkmcnt(0)" ::: "memory");
    __builtin_amdgcn_s_barrier();
}

// Persistent: 256 blocks (1/CU). Block p: batch b=p&7 (image pinned to one
// XCD), tiles tl = idx32 + 32*j, row-major (ty=tl>>3, tx=tl&7): at any phase
// the 32 blocks of an image cover 4 FULL tile-rows -> contiguous 960-px image
// row coverage per plane, 512 B segments per block (vs 256 B at 64-wide).
// 2-deep register prefetch pipeline across tiles (counted vmcnt, raw barrier).
__global__ __launch_bounds__(1024, 4) void affprop_persist(
    const float* __restrict__ aff,
    const float* __restrict__ feat,
    float* __restrict__ out)
{
    __shared__ float4 lds4[2 * LBUF];

    const int tid   = threadIdx.x;
    const int q     = tid & 31;            // quad 0..31 (region 128 px wide)
    const int ry    = tid >> 5;            // region row 0..31
    const int p     = blockIdx.x;
    const int b     = p & 7;
    const int idx32 = p >> 3;              // 0..31
    const int NT    = (idx32 < TPB - 32 * 5) ? 6 : 5;   // 24 runs of 6, 8 of 5

    const float* abase = aff  + (size_t)b * 9 * HWSZ;
    const float* fbase = feat + (size_t)b * HWSZ;
    float*       obase = out  + (size_t)b * HWSZ;

    // zero the 4 ring rows (rows 0,33 of both buffers) once; never touched again
    if (tid < 128) {
        const int buf = tid >> 6;
        const int row = ((tid >> 5) & 1) ? (LROWS - 1) : 0;
        lds4[buf * LBUF + row * LCELLS + (tid & 31)] = make_float4(0.f, 0.f, 0.f, 0.f);
    }

    // tile tl: ty = tl>>3, tx = tl&7
    auto issue = [&](int jt, float4 (&raw)[10]) {
        const int tl = idx32 + 32 * jt;
        const int ty = tl >> 3, tx = tl & 7;
        const int yimg = ty * OTY - 4 + ry;
        const int xq   = tx * OTX - 4 + 4 * q;
        const bool inp = (yimg >= 0) && (yimg < HH) && (xq >= 0) && (xq < WW);
        const bool wr  = inp && (ry >= 1) && (ry <= 30);
#pragma unroll
        for (int c = 0; c < 10; ++c) raw[c] = make_float4(0.f, 0.f, 0.f, 0.f);
        if (inp)
            raw[9] = *reinterpret_cast<const float4*>(fbase + (size_t)yimg * WW + xq);
        if (wr) {
            const float* ap = abase + (size_t)yimg * WW + xq;
#pragma unroll
            for (int c = 0; c < 9; ++c)
                raw[c] = *reinterpret_cast<const float4*>(ap + (size_t)c * HWSZ);
        }
        __builtin_amdgcn_sched_barrier(0);   // pin load issue here
    };

    auto compute = [&](int jt, float4 (&raw)[10]) {
        const int tl = idx32 + 32 * jt;
        const int ty = tl >> 3, tx = tl & 7;
        const int oy = ty * OTY - 4, ox = tx * OTX - 4;
        const int yimg = oy + ry;
        const int xq   = ox + 4 * q;
        const bool wr = (yimg >= 0) && (yimg < HH) && (xq >= 0) && (xq < WW)
                        && (ry >= 1) && (ry <= 30);

        // normalize in place (first consume of raw -> counted vmcnt wait here)
        if (wr) {
            float4 s = make_float4(0.f, 0.f, 0.f, 0.f);
#pragma unroll
            for (int c = 0; c < 9; ++c) {
                raw[c].x = fabsf(raw[c].x); s.x += raw[c].x;
                raw[c].y = fabsf(raw[c].y); s.y += raw[c].y;
                raw[c].z = fabsf(raw[c].z); s.z += raw[c].z;
                raw[c].w = fabsf(raw[c].w); s.w += raw[c].w;
            }
            float4 r;
            r.x = 1.0f / s.x; r.y = 1.0f / s.y; r.z = 1.0f / s.z; r.w = 1.0f / s.w;
#pragma unroll
            for (int c = 0; c < 9; ++c) {
                raw[c].x *= r.x; raw[c].y *= r.y; raw[c].z *= r.z; raw[c].w *= r.w;
            }
        }
        // non-wr lanes: raw == 0 -> weights 0 -> acc stays 0 (zero-pad ring)

        lds4[(ry + 1) * LCELLS + q] = raw[9];   // buf0 init store
        bar();

        float4 acc;
        int bufr = 0;
#pragma unroll
        for (int it = 0; it < 4; ++it) {
            acc = make_float4(0.f, 0.f, 0.f, 0.f);
#pragma unroll
            for (int r = 0; r < 3; ++r) {
                const float4 m = lds4[bufr * LBUF + (ry + r) * LCELLS + q];
                // rows of 32 quads = half-wave; q==0 / q==31 edges are masked,
                // so shfl leakage across the half-wave boundary is discarded
                float left  = __shfl_up(m.w, 1);   if (q == 0)  left  = 0.f;
                float right = __shfl_down(m.x, 1); if (q == 31) right = 0.f;
                const float4 wl  = raw[3 * r + 0];
                const float4 wc  = raw[3 * r + 1];
                const float4 wrr = raw[3 * r + 2];
                acc.x = fmaf(wl.x, left, fmaf(wc.x, m.x, fmaf(wrr.x, m.y, acc.x)));
                acc.y = fmaf(wl.y, m.x,  fmaf(wc.y, m.y, fmaf(wrr.y, m.z, acc.y)));
                acc.z = fmaf(wl.z, m.y,  fmaf(wc.z, m.z, fmaf(wrr.z, m.w, acc.z)));
                acc.w = fmaf(wl.w, m.z,  fmaf(wc.w, m.w, fmaf(wrr.w, right, acc.w)));
            }
            if (it < 3) {
                lds4[(bufr ^ 1) * LBUF + (ry + 1) * LCELLS + q] = acc;
                bar();
                bufr ^= 1;
            }
        }

        if (ry >= 4 && ry < 4 + OTY && q >= 1 && q < 31) {
            const int yo = oy + ry, xo = ox + 4 * q;
            if (yo < HH && xo < WW)
                *reinterpret_cast<float4*>(obase + (size_t)yo * WW + xo) = acc;
        }
    };

    float4 A[10], B[10];
    issue(0, A);
    int j = 0;
    while (true) {
        if (j + 1 < NT) issue(j + 1, B);
        compute(j, A);
        if (++j >= NT) break;
        if (j + 1 < NT) issue(j + 1, A);
        compute(j, B);
        if (++j >= NT) break;
    }
}

extern "C" void kernel_launch(void* const* d_in, const int* in_sizes, int n_in,
                              void* d_out, int out_size, void* d_ws, size_t ws_size,
                              hipStream_t stream) {
    const float* aff  = (const float*)d_in[0];
    const float* feat = (const float*)d_in[1];
    float* out = (float*)d_out;
    (void)d_ws; (void)ws_size;

    affprop_persist<<<256, 1024, 0, stream>>>(aff, feat, out);
}

// Round 10
// 40.649 us; speedup vs baseline: 1.2034x; 1.2034x over previous
//
#include <hip/hip_runtime.h>

#define BATCH 8
#define HH 544
#define WW 960
#define HWSZ (HH * WW)
#define OT 56             // output tile edge (56x56), region 64x64
#define LROWS 66          // region rows -1..64 at LDS rows 0..65 (0,65 = zero ring)
#define LCELLS 16         // 16 quads per row; x-halo via shfl
#define LBUF (LROWS * LCELLS)
#define NTX 18            // tile columns per image
#define NTY 10            // tile rows per image
#define TPB (NTX * NTY)   // 180 tiles per batch image

static __device__ __forceinline__ void bar() {
    // order LDS only; leave global prefetch loads in flight across the barrier
    asm volatile("s_waitcnt lgkmcnt(0)" ::: "memory");
    __builtin_amdgcn_s_barrier();
}

// Persistent: 256 blocks. Block p: batch b=p&7 (image pinned to one XCD),
// tiles tl = idx32 + 32*j, ROW-MAJOR decode: at any step j the 32 blocks of an
// image cover ~2 consecutive tile-rows -> collectively they read full
// contiguous image rows per plane (DRAM-page-friendly) and share halos in L2.
// 2-deep register prefetch pipeline across tiles (counted vmcnt, raw barrier).
__global__ __launch_bounds__(1024, 4) void affprop_persist(
    const float* __restrict__ aff,
    const float* __restrict__ feat,
    float* __restrict__ out)
{
    __shared__ float4 lds4[2 * LBUF];

    const int tid   = threadIdx.x;
    const int q     = tid & 15;
    const int ry    = tid >> 4;            // 0..63
    const int p     = blockIdx.x;
    const int b     = p & 7;
    const int idx32 = p >> 3;              // 0..31
    const int NT    = (idx32 < TPB - 32 * 5) ? 6 : 5;   // 20 runs of 6, 12 of 5

    const float* abase = aff  + (size_t)b * 9 * HWSZ;
    const float* fbase = feat + (size_t)b * HWSZ;
    float*       obase = out  + (size_t)b * HWSZ;

    // zero the 4 ring rows (rows 0,65 of both buffers) once; never touched again
    if (tid < 64) {
        const int buf = tid >> 5;
        const int row = ((tid >> 4) & 1) ? (LROWS - 1) : 0;
        lds4[buf * LBUF + row * LCELLS + (tid & 15)] = make_float4(0.f, 0.f, 0.f, 0.f);
    }

    // tile tl (row-major): ty = tl/NTX, tx = tl%NTX
    auto issue = [&](int jt, float4 (&raw)[10]) {
        const int tl = idx32 + 32 * jt;
        const int ty = tl / NTX, tx = tl - ty * NTX;
        const int yimg = ty * OT - 4 + ry;
        const int xq   = tx * OT - 4 + 4 * q;
        const bool inp = (yimg >= 0) && (yimg < HH) && (xq >= 0) && (xq < WW);
        const bool wr  = inp && (ry >= 1) && (ry <= 62);
#pragma unroll
        for (int c = 0; c < 10; ++c) raw[c] = make_float4(0.f, 0.f, 0.f, 0.f);
        if (inp)
            raw[9] = *reinterpret_cast<const float4*>(fbase + (size_t)yimg * WW + xq);
        if (wr) {
            const float* ap = abase + (size_t)yimg * WW + xq;
#pragma unroll
            for (int c = 0; c < 9; ++c)
                raw[c] = *reinterpret_cast<const float4*>(ap + (size_t)c * HWSZ);
        }
        __builtin_amdgcn_sched_barrier(0);   // pin load issue here
    };

    auto compute = [&](int jt, float4 (&raw)[10]) {
        const int tl = idx32 + 32 * jt;
        const int ty = tl / NTX, tx = tl - ty * NTX;
        const int oy = ty * OT - 4, ox = tx * OT - 4;
        const int yimg = oy + ry;
        const int xq   = ox + 4 * q;
        const bool wr = (yimg >= 0) && (yimg < HH) && (xq >= 0) && (xq < WW)
                        && (ry >= 1) && (ry <= 62);

        // normalize in place (first consume of raw -> counted vmcnt wait here)
        if (wr) {
            float4 s = make_float4(0.f, 0.f, 0.f, 0.f);
#pragma unroll
            for (int c = 0; c < 9; ++c) {
                raw[c].x = fabsf(raw[c].x); s.x += raw[c].x;
                raw[c].y = fabsf(raw[c].y); s.y += raw[c].y;
                raw[c].z = fabsf(raw[c].z); s.z += raw[c].z;
                raw[c].w = fabsf(raw[c].w); s.w += raw[c].w;
            }
            float4 r;
            r.x = 1.0f / s.x; r.y = 1.0f / s.y; r.z = 1.0f / s.z; r.w = 1.0f / s.w;
#pragma unroll
            for (int c = 0; c < 9; ++c) {
                raw[c].x *= r.x; raw[c].y *= r.y; raw[c].z *= r.z; raw[c].w *= r.w;
            }
        }
        // non-wr lanes: raw == 0 -> weights 0 -> acc stays 0 (zero-pad ring)

        lds4[(ry + 1) * LCELLS + q] = raw[9];   // buf0 init store
        bar();

        float4 acc;
        int bufr = 0;
#pragma unroll
        for (int it = 0; it < 4; ++it) {
            acc = make_float4(0.f, 0.f, 0.f, 0.f);
#pragma unroll
            for (int r = 0; r < 3; ++r) {
                const float4 m = lds4[bufr * LBUF + (ry + r) * LCELLS + q];
                float left  = __shfl_up(m.w, 1);   if (q == 0)  left  = 0.f;
                float right = __shfl_down(m.x, 1); if (q == 15) right = 0.f;
                const float4 wl  = raw[3 * r + 0];
                const float4 wc  = raw[3 * r + 1];
                const float4 wrr = raw[3 * r + 2];
                acc.x = fmaf(wl.x, left, fmaf(wc.x, m.x, fmaf(wrr.x, m.y, acc.x)));
                acc.y = fmaf(wl.y, m.x,  fmaf(wc.y, m.y, fmaf(wrr.y, m.z, acc.y)));
                acc.z = fmaf(wl.z, m.y,  fmaf(wc.z, m.z, fmaf(wrr.z, m.w, acc.z)));
                acc.w = fmaf(wl.w, m.z,  fmaf(wc.w, m.w, fmaf(wrr.w, right, acc.w)));
            }
            if (it < 3) {
                lds4[(bufr ^ 1) * LBUF + (ry + 1) * LCELLS + q] = acc;
                bar();
                bufr ^= 1;
            }
        }

        if (ry >= 4 && ry < 4 + OT && q >= 1 && q < 15) {
            const int yo = oy + ry, xo = ox + 4 * q;
            if (yo < HH && xo < WW)
                *reinterpret_cast<float4*>(obase + (size_t)yo * WW + xo) = acc;
        }
    };

    float4 A[10], B[10];
    issue(0, A);
    int j = 0;
    while (true) {
        if (j + 1 < NT) issue(j + 1, B);
        compute(j, A);
        if (++j >= NT) break;
        if (j + 1 < NT) issue(j + 1, A);
        compute(j, B);
        if (++j >= NT) break;
    }
}

extern "C" void kernel_launch(void* const* d_in, const int* in_sizes, int n_in,
                              void* d_out, int out_size, void* d_ws, size_t ws_size,
                              hipStream_t stream) {
    const float* aff  = (const float*)d_in[0];
    const float* feat = (const float*)d_in[1];
    float* out = (float*)d_out;
    (void)d_ws; (void)ws_size;

    affprop_persist<<<256, 1024, 0, stream>>>(aff, feat, out);
}